// Round 1
// baseline (857.358 us; speedup 1.0000x reference)
//
#include <hip/hip_runtime.h>
#include <math.h>

#define ZB 2
#define NN 4096
#define KNNv 30
#define EDIM 256
#define DM 128

// ---------------- KNN: one block per (z,i) ----------------
__global__ __launch_bounds__(256) void knn_kernel(
    const float* __restrict__ C,              // (Z,N,4,3)
    const unsigned char* __restrict__ node_mask, // (Z,N) bool
    float* __restrict__ out_kidx,             // (Z,N,30) as float
    float* __restrict__ out_emask)            // (Z,N,30) as float 0/1
{
    __shared__ float sqd[NN];
    __shared__ float red_v[4];
    __shared__ int   red_i[4];
    __shared__ float sel_v[KNNv];
    __shared__ int   sel_i[KNNv];

    const int bi = blockIdx.x;            // z*NN + i
    const int z  = bi >> 12;
    const int i  = bi & (NN - 1);
    const int t  = threadIdx.x;

    const float* ca = C + ((size_t)bi * 4 + 1) * 3;   // Ca[z,i] = C[z,i,1,:]
    const float xi = ca[0], yi = ca[1], zi = ca[2];
    const bool mask_i = node_mask[bi] != 0;

    const float* Cz = C + (size_t)z * NN * 12 + 3;    // atom-1 base for batch z
    for (int j = t; j < NN; j += 256) {
        const float* cj = Cz + (size_t)j * 12;
        float dx = cj[0] - xi, dy = cj[1] - yi, dz = cj[2] - zi;
        float s = dx * dx + dy * dy + dz * dz;
        if (s == 0.0f || mask_i) s = __builtin_inff();
        sqd[j] = s;
    }
    __syncthreads();

    // 30 extraction passes; NaN-poison selected entries so ties advance by index
    for (int k = 0; k < KNNv; ++k) {
        float bv = __builtin_inff(); int bj = NN;
        for (int j = t; j < NN; j += 256) {
            float s = sqd[j];                 // NaN compares false -> skipped
            if (s < bv || (s == bv && j < bj)) { bv = s; bj = j; }
        }
        #pragma unroll
        for (int off = 32; off > 0; off >>= 1) {
            float ov = __shfl_down(bv, off);
            int   oj = __shfl_down(bj, off);
            if (ov < bv || (ov == bv && oj < bj)) { bv = ov; bj = oj; }
        }
        if ((t & 63) == 0) { red_v[t >> 6] = bv; red_i[t >> 6] = bj; }
        __syncthreads();
        if (t == 0) {
            bv = red_v[0]; bj = red_i[0];
            for (int w = 1; w < 4; ++w)
                if (red_v[w] < bv || (red_v[w] == bv && red_i[w] < bj)) { bv = red_v[w]; bj = red_i[w]; }
            sel_v[k] = bv; sel_i[k] = bj;
            sqd[bj] = __builtin_nanf("");
        }
        __syncthreads();
    }

    if (t < KNNv) {
        float sv = sel_v[t]; int j = sel_i[t];
        bool nb = node_mask[(size_t)z * NN + j] != 0;
        bool em = (!mask_i && !nb) && (sv != 0.0f) && (sv < 144.0f);
        int kv = em ? j : i;
        size_t o = (size_t)bi * KNNv + t;
        out_kidx[o]  = (float)kv;
        out_emask[o] = em ? 1.0f : 0.0f;
    }
}

// ---------------- Edges: one block per 64 edges ----------------
// Phase 1: RBF + layernorm -> LDS Eln[p][e] (transposed, 64 KiB exactly)
// Phase 2: register-blocked fp32 GEMM 64x256 @ 256x128
__global__ __launch_bounds__(256) void edge_kernel(
    const float* __restrict__ C,
    const float* __restrict__ kidxf,     // (Z,N,30) float (read back from d_out)
    const float* __restrict__ centers,   // 16
    const float* __restrict__ gamma_,    // 256
    const float* __restrict__ beta_,     // 256
    const float* __restrict__ W,         // 256x128
    const float* __restrict__ bias,      // 128
    float* __restrict__ outE)            // (Z,N,30,128)
{
    __shared__ float Eln[EDIM * 64];     // [p][e], stride 64 -> conflict-free f4 reads
    const int t = threadIdx.x;
    const long g0 = (long)blockIdx.x * 64;

    // ---- phase 1: 4 threads per edge, each handles atom a = sub (64 features)
    {
        const int e   = t >> 2;          // 0..63 local edge
        const int sub = t & 3;           // atom a index
        const long g = g0 + e;
        const int z   = (int)(g / (NN * KNNv));
        const int rem = (int)(g - (long)z * NN * KNNv);
        const int i   = rem / KNNv;
        const int j   = (int)kidxf[g];

        const float* Ci = C + (((size_t)z * NN + i) * 4 + sub) * 3;
        const float ax = Ci[0], ay = Ci[1], az = Ci[2];
        const float* Cj = C + ((size_t)z * NN + j) * 12;
        float d[4];
        #pragma unroll
        for (int b = 0; b < 4; ++b) {
            float dx = ax - Cj[b * 3 + 0];
            float dy = ay - Cj[b * 3 + 1];
            float dz = az - Cj[b * 3 + 2];
            float s = dx * dx + dy * dy + dz * dz;
            d[b] = s > 0.0f ? sqrtf(s) : 0.0f;     // _safe_dist
        }
        float cen[16];
        #pragma unroll
        for (int r = 0; r < 16; ++r) cen[r] = centers[r];

        float vals[64];
        float sum = 0.f, sumsq = 0.f;
        #pragma unroll
        for (int b = 0; b < 4; ++b) {
            #pragma unroll
            for (int r = 0; r < 16; ++r) {
                float dd = d[b] - cen[r];
                float v = __expf(dd * dd * -0.64f);   // 1/SPREAD^2 = 0.64
                vals[b * 16 + r] = v;
                sum += v; sumsq += v * v;
            }
        }
        // LN stats over the 4 lanes of this edge (lanes 4e..4e+3, same wave)
        sum   += __shfl_xor(sum, 1);   sum   += __shfl_xor(sum, 2);
        sumsq += __shfl_xor(sumsq, 1); sumsq += __shfl_xor(sumsq, 2);
        const float mu   = sum * (1.0f / 256.0f);
        const float var  = sumsq * (1.0f / 256.0f) - mu * mu;
        const float rstd = rsqrtf(var + 1e-5f);
        #pragma unroll
        for (int q = 0; q < 64; ++q) {
            int p = sub * 64 + q;
            float y = (vals[q] - mu) * rstd * gamma_[p] + beta_[p];
            Eln[p * 64 + e] = y;
        }
    }
    __syncthreads();

    // ---- phase 2: thread -> (edge group eg: 4 edges, col group c: 8 cols)
    {
        const int c  = t & 15;
        const int eg = t >> 4;
        const int n0 = c * 8;
        float acc[4][8];
        #pragma unroll
        for (int r = 0; r < 4; ++r)
            #pragma unroll
            for (int n = 0; n < 8; ++n) acc[r][n] = 0.f;

        const float*  Wp = W + n0;
        const float4* Ep = (const float4*)(Eln) + eg;   // Eln[kk*64 + eg*4]
        #pragma unroll 4
        for (int kk = 0; kk < EDIM; ++kk) {
            float4 ev = Ep[kk * 16];
            float4 w0 = *(const float4*)(Wp + kk * DM);
            float4 w1 = *(const float4*)(Wp + kk * DM + 4);
            const float e4[4] = {ev.x, ev.y, ev.z, ev.w};
            #pragma unroll
            for (int r = 0; r < 4; ++r) {
                float e = e4[r];
                acc[r][0] += e * w0.x; acc[r][1] += e * w0.y;
                acc[r][2] += e * w0.z; acc[r][3] += e * w0.w;
                acc[r][4] += e * w1.x; acc[r][5] += e * w1.y;
                acc[r][6] += e * w1.z; acc[r][7] += e * w1.w;
            }
        }
        float4 b0 = *(const float4*)(bias + n0);
        float4 b1 = *(const float4*)(bias + n0 + 4);
        #pragma unroll
        for (int r = 0; r < 4; ++r) {
            float* orow = outE + (size_t)(g0 + eg * 4 + r) * DM + n0;
            float4 o0 = make_float4(acc[r][0] + b0.x, acc[r][1] + b0.y,
                                    acc[r][2] + b0.z, acc[r][3] + b0.w);
            float4 o1 = make_float4(acc[r][4] + b1.x, acc[r][5] + b1.y,
                                    acc[r][6] + b1.z, acc[r][7] + b1.w);
            *(float4*)(orow)     = o0;
            *(float4*)(orow + 4) = o1;
        }
    }
}

extern "C" void kernel_launch(void* const* d_in, const int* in_sizes, int n_in,
                              void* d_out, int out_size, void* d_ws, size_t ws_size,
                              hipStream_t stream) {
    const float* C        = (const float*)d_in[0];
    const unsigned char* nm = (const unsigned char*)d_in[1];
    const float* centers  = (const float*)d_in[2];
    const float* gamma_   = (const float*)d_in[3];
    const float* beta_    = (const float*)d_in[4];
    const float* W        = (const float*)d_in[5];
    const float* bias     = (const float*)d_in[6];

    float* out = (float*)d_out;
    const size_t nE = (size_t)ZB * NN * KNNv * DM;   // 31,457,280
    const size_t nK = (size_t)ZB * NN * KNNv;        //    245,760
    float* outE = out;
    float* outK = out + nE;
    float* outM = outK + nK;

    knn_kernel<<<ZB * NN, 256, 0, stream>>>(C, nm, outK, outM);
    edge_kernel<<<(int)(nK / 64), 256, 0, stream>>>(C, outK, centers, gamma_, beta_, W, bias, outE);
}

// Round 2
// 491.615 us; speedup vs baseline: 1.7440x; 1.7440x over previous
//
#include <hip/hip_runtime.h>
#include <math.h>

#define ZB 2
#define NN 4096
#define KNNv 30
#define EDIM 256
#define DM 128
#define BINS 4096
#define CAP 2048

// ---------------- KNN via single-pass radix select: one block per (z,i) ----
__global__ __launch_bounds__(256) void knn_kernel(
    const float* __restrict__ C,                 // (Z,N,4,3)
    const unsigned char* __restrict__ node_mask, // (Z,N) bool
    float* __restrict__ out_kidx,                // (Z,N,30) as float
    float* __restrict__ out_emask)               // (Z,N,30) as float 0/1
{
    __shared__ unsigned int hist[BINS];          // 12-bit-key histogram
    __shared__ unsigned long long buf[CAP];      // candidate (key<<32)|idx
    __shared__ unsigned int wsum[4];
    __shared__ int s_cut;
    __shared__ unsigned int s_m;
    __shared__ unsigned long long sel[KNNv];

    const int bi = blockIdx.x;            // z*NN + i
    const int z  = bi >> 12;
    const int i  = bi & (NN - 1);
    const int t  = threadIdx.x;

    for (int q = t; q < BINS; q += 256) hist[q] = 0u;
    if (t == 0) s_m = 0u;
    __syncthreads();

    const float* ca = C + ((size_t)bi * 4 + 1) * 3;   // Ca[z,i]
    const float xi = ca[0], yi = ca[1], zi = ca[2];
    const bool mask_i = node_mask[bi] != 0;
    const float* Cz = C + (size_t)z * NN * 12 + 3;    // atom-1 base, batch z

    unsigned int keys[16];
    #pragma unroll
    for (int q = 0; q < 16; ++q) {
        const int j = q * 256 + t;
        const float* cj = Cz + (size_t)j * 12;
        float dx = cj[0] - xi, dy = cj[1] - yi, dz = cj[2] - zi;
        float s = dx * dx + dy * dy + dz * dz;
        if (s == 0.0f || mask_i) s = __builtin_inff();
        unsigned int k = __float_as_uint(s);          // positive floats: order-preserving
        keys[q] = k;
        atomicAdd(&hist[k >> 20], 1u);
    }
    __syncthreads();

    // exclusive block scan over the 4096 bins (16 per thread, bins in t*16+q order)
    unsigned int cnt[16]; unsigned int Tsum = 0;
    #pragma unroll
    for (int q = 0; q < 16; ++q) { cnt[q] = hist[t * 16 + q]; Tsum += cnt[q]; }
    unsigned int incl = Tsum;
    #pragma unroll
    for (int off = 1; off < 64; off <<= 1) {
        unsigned int v = __shfl_up(incl, off);
        if ((t & 63) >= off) incl += v;
    }
    if ((t & 63) == 63) wsum[t >> 6] = incl;
    __syncthreads();
    unsigned int woff = 0;
    for (int w = 0; w < (t >> 6); ++w) woff += wsum[w];
    unsigned int run = woff + incl - Tsum;            // exclusive prefix of bin t*16
    #pragma unroll
    for (int q = 0; q < 16; ++q) {
        unsigned int c = cnt[q];
        if (run < KNNv && run + c >= KNNv) s_cut = t * 16 + q;  // unique writer
        run += c;
    }
    __syncthreads();

    // collect candidates: all elements in bins <= cut (>=30 of them, ~tens typical)
    const int cutbin = s_cut;
    #pragma unroll
    for (int q = 0; q < 16; ++q) {
        unsigned int k = keys[q];
        if ((int)(k >> 20) <= cutbin) {
            unsigned int pos = atomicAdd(&s_m, 1u);
            if (pos < CAP)
                buf[pos] = ((unsigned long long)k << 32) | (unsigned int)(q * 256 + t);
        }
    }
    __syncthreads();
    unsigned int M = s_m; if (M > CAP) M = CAP;

    // rank-order the candidates; packed compare == (key asc, idx asc) == jax top_k
    for (unsigned int c = t; c < M; c += 256) {
        unsigned long long me = buf[c];
        unsigned int r = 0;
        for (unsigned int o = 0; o < M; ++o) r += (buf[o] < me) ? 1u : 0u;
        if (r < KNNv) sel[r] = me;
    }
    __syncthreads();

    if (t < KNNv) {
        unsigned long long p = sel[t];
        unsigned int k = (unsigned int)(p >> 32);
        int j = (int)(p & 0xffffffffu);
        float sv = __uint_as_float(k);
        bool nb = node_mask[(size_t)z * NN + j] != 0;
        bool em = (!mask_i && !nb) && (sv != 0.0f) && (sv < 144.0f);
        int kv = em ? j : i;
        size_t o = (size_t)bi * KNNv + t;
        out_kidx[o]  = (float)kv;
        out_emask[o] = em ? 1.0f : 0.0f;
    }
}

// ---------------- Edges: one block per 64 edges ----------------
__global__ __launch_bounds__(256) void edge_kernel(
    const float* __restrict__ C,
    const float* __restrict__ kidxf,     // (Z,N,30) float
    const float* __restrict__ centers,   // 16
    const float* __restrict__ gamma_,    // 256
    const float* __restrict__ beta_,     // 256
    const float* __restrict__ W,         // 256x128
    const float* __restrict__ bias,      // 128
    float* __restrict__ outE)            // (Z,N,30,128)
{
    __shared__ float Eln[EDIM * 64];     // [p][e]
    const int t = threadIdx.x;
    const long g0 = (long)blockIdx.x * 64;

    {
        const int e   = t >> 2;
        const int sub = t & 3;
        const long g = g0 + e;
        const int z   = (int)(g / (NN * KNNv));
        const int rem = (int)(g - (long)z * NN * KNNv);
        const int i   = rem / KNNv;
        const int j   = (int)kidxf[g];

        const float* Ci = C + (((size_t)z * NN + i) * 4 + sub) * 3;
        const float ax = Ci[0], ay = Ci[1], az = Ci[2];
        const float* Cj = C + ((size_t)z * NN + j) * 12;
        float d[4];
        #pragma unroll
        for (int b = 0; b < 4; ++b) {
            float dx = ax - Cj[b * 3 + 0];
            float dy = ay - Cj[b * 3 + 1];
            float dz = az - Cj[b * 3 + 2];
            float s = dx * dx + dy * dy + dz * dz;
            d[b] = s > 0.0f ? sqrtf(s) : 0.0f;
        }
        float cen[16];
        #pragma unroll
        for (int r = 0; r < 16; ++r) cen[r] = centers[r];

        float vals[64];
        float sum = 0.f, sumsq = 0.f;
        #pragma unroll
        for (int b = 0; b < 4; ++b) {
            #pragma unroll
            for (int r = 0; r < 16; ++r) {
                float dd = d[b] - cen[r];
                float v = __expf(dd * dd * -0.64f);
                vals[b * 16 + r] = v;
                sum += v; sumsq += v * v;
            }
        }
        sum   += __shfl_xor(sum, 1);   sum   += __shfl_xor(sum, 2);
        sumsq += __shfl_xor(sumsq, 1); sumsq += __shfl_xor(sumsq, 2);
        const float mu   = sum * (1.0f / 256.0f);
        const float var  = sumsq * (1.0f / 256.0f) - mu * mu;
        const float rstd = rsqrtf(var + 1e-5f);
        #pragma unroll
        for (int q = 0; q < 64; ++q) {
            int p = sub * 64 + q;
            float y = (vals[q] - mu) * rstd * gamma_[p] + beta_[p];
            Eln[p * 64 + e] = y;
        }
    }
    __syncthreads();

    {
        const int c  = t & 15;
        const int eg = t >> 4;
        const int n0 = c * 8;
        float acc[4][8];
        #pragma unroll
        for (int r = 0; r < 4; ++r)
            #pragma unroll
            for (int n = 0; n < 8; ++n) acc[r][n] = 0.f;

        const float*  Wp = W + n0;
        const float4* Ep = (const float4*)(Eln) + eg;
        #pragma unroll 4
        for (int kk = 0; kk < EDIM; ++kk) {
            float4 ev = Ep[kk * 16];
            float4 w0 = *(const float4*)(Wp + kk * DM);
            float4 w1 = *(const float4*)(Wp + kk * DM + 4);
            const float e4[4] = {ev.x, ev.y, ev.z, ev.w};
            #pragma unroll
            for (int r = 0; r < 4; ++r) {
                float e = e4[r];
                acc[r][0] += e * w0.x; acc[r][1] += e * w0.y;
                acc[r][2] += e * w0.z; acc[r][3] += e * w0.w;
                acc[r][4] += e * w1.x; acc[r][5] += e * w1.y;
                acc[r][6] += e * w1.z; acc[r][7] += e * w1.w;
            }
        }
        float4 b0 = *(const float4*)(bias + n0);
        float4 b1 = *(const float4*)(bias + n0 + 4);
        #pragma unroll
        for (int r = 0; r < 4; ++r) {
            float* orow = outE + (size_t)(g0 + eg * 4 + r) * DM + n0;
            *(float4*)(orow)     = make_float4(acc[r][0] + b0.x, acc[r][1] + b0.y,
                                               acc[r][2] + b0.z, acc[r][3] + b0.w);
            *(float4*)(orow + 4) = make_float4(acc[r][4] + b1.x, acc[r][5] + b1.y,
                                               acc[r][6] + b1.z, acc[r][7] + b1.w);
        }
    }
}

extern "C" void kernel_launch(void* const* d_in, const int* in_sizes, int n_in,
                              void* d_out, int out_size, void* d_ws, size_t ws_size,
                              hipStream_t stream) {
    const float* C          = (const float*)d_in[0];
    const unsigned char* nm = (const unsigned char*)d_in[1];
    const float* centers    = (const float*)d_in[2];
    const float* gamma_     = (const float*)d_in[3];
    const float* beta_      = (const float*)d_in[4];
    const float* W          = (const float*)d_in[5];
    const float* bias       = (const float*)d_in[6];

    float* out = (float*)d_out;
    const size_t nE = (size_t)ZB * NN * KNNv * DM;
    const size_t nK = (size_t)ZB * NN * KNNv;
    float* outE = out;
    float* outK = out + nE;
    float* outM = outK + nK;

    knn_kernel<<<ZB * NN, 256, 0, stream>>>(C, nm, outK, outM);
    edge_kernel<<<(int)(nK / 64), 256, 0, stream>>>(C, outK, centers, gamma_, beta_, W, bias, outE);
}

// Round 3
// 243.946 us; speedup vs baseline: 3.5145x; 2.0153x over previous
//
#include <hip/hip_runtime.h>
#include <math.h>

#define ZB 2
#define NN 4096
#define KNNv 30
#define EDIM 256
#define DM 128
#define BINS 4096
#define CAP 2048

typedef __attribute__((ext_vector_type(8))) short bf16x8;
typedef __attribute__((ext_vector_type(4))) float fx4;

// Eln LDS row stride in bf16 elements: 256 + 8 pad -> A-frag ds_read_b128 is
// 2-way bank aliased (free per m136); 16B-aligned everywhere (264*2=528=33*16).
#define ELN_STR 264

static __device__ inline unsigned short f2bf(float f) {
    unsigned int u = __float_as_uint(f);
    unsigned int r = u + 0x7fffu + ((u >> 16) & 1u);   // RNE
    return (unsigned short)(r >> 16);
}

// ---- prep: dense Ca as float4 (x,y,z,0) --------------------------------
__global__ __launch_bounds__(256) void caprep_kernel(
    const float* __restrict__ C, float4* __restrict__ Ca4)
{
    int tid = blockIdx.x * 256 + threadIdx.x;           // 0..8191
    if (tid < ZB * NN) {
        const float* p = C + (size_t)tid * 12 + 3;      // atom 1
        Ca4[tid] = make_float4(p[0], p[1], p[2], 0.0f);
    }
}

// ---- prep: Wt[n][k] = bf16(W[k][n] * gamma[k]) (128 x 256) -------------
__global__ __launch_bounds__(256) void wprep_kernel(
    const float* __restrict__ W, const float* __restrict__ gamma_,
    unsigned short* __restrict__ Wt)
{
    int base = blockIdx.x * 1024 + threadIdx.x;         // 32 blocks x 4 elems
    #pragma unroll
    for (int q = 0; q < 4; ++q) {
        int idx = base + q * 256;                       // idx = k*128 + n
        int k = idx >> 7, n = idx & 127;
        Wt[n * 256 + k] = f2bf(W[idx] * gamma_[k]);
    }
}

// ---- prep: bias2[n] = b[n] + sum_k beta[k]*W[k][n] ---------------------
__global__ __launch_bounds__(128) void biasprep_kernel(
    const float* __restrict__ W, const float* __restrict__ beta_,
    const float* __restrict__ bias, float* __restrict__ bias2)
{
    int n = threadIdx.x;
    float acc = bias[n];
    #pragma unroll 8
    for (int k = 0; k < EDIM; ++k) acc += beta_[k] * W[k * 128 + n];
    bias2[n] = acc;
}

// ---------------- KNN via single-pass radix select ----------------------
__global__ __launch_bounds__(256) void knn_kernel(
    const float4* __restrict__ Ca4,              // dense (Z*N) x float4
    const unsigned char* __restrict__ node_mask,
    float* __restrict__ out_kidx,
    float* __restrict__ out_emask)
{
    __shared__ unsigned int hist[BINS];
    __shared__ unsigned long long buf[CAP];
    __shared__ unsigned int wsum[4];
    __shared__ int s_cut;
    __shared__ unsigned int s_m;
    __shared__ unsigned long long sel[KNNv];

    const int bi = blockIdx.x;
    const int z  = bi >> 12;
    const int i  = bi & (NN - 1);
    const int t  = threadIdx.x;

    for (int q = t; q < BINS; q += 256) hist[q] = 0u;
    if (t == 0) s_m = 0u;
    __syncthreads();

    const float4 me = Ca4[bi];
    const float xi = me.x, yi = me.y, zi = me.z;
    const bool mask_i = node_mask[bi] != 0;
    const float4* Cz = Ca4 + ((size_t)z << 12);

    unsigned int keys[16];
    #pragma unroll
    for (int q = 0; q < 16; ++q) {
        const int j = q * 256 + t;
        float4 p = Cz[j];
        float dx = p.x - xi, dy = p.y - yi, dz = p.z - zi;
        float s = dx * dx + dy * dy + dz * dz;
        if (s == 0.0f || mask_i) s = __builtin_inff();
        unsigned int k = __float_as_uint(s);
        keys[q] = k;
        atomicAdd(&hist[k >> 20], 1u);
    }
    __syncthreads();

    unsigned int cnt[16]; unsigned int Tsum = 0;
    #pragma unroll
    for (int q = 0; q < 16; ++q) { cnt[q] = hist[t * 16 + q]; Tsum += cnt[q]; }
    unsigned int incl = Tsum;
    #pragma unroll
    for (int off = 1; off < 64; off <<= 1) {
        unsigned int v = __shfl_up(incl, off);
        if ((t & 63) >= off) incl += v;
    }
    if ((t & 63) == 63) wsum[t >> 6] = incl;
    __syncthreads();
    unsigned int woff = 0;
    for (int w = 0; w < (t >> 6); ++w) woff += wsum[w];
    unsigned int run = woff + incl - Tsum;
    #pragma unroll
    for (int q = 0; q < 16; ++q) {
        unsigned int c = cnt[q];
        if (run < KNNv && run + c >= KNNv) s_cut = t * 16 + q;
        run += c;
    }
    __syncthreads();

    const int cutbin = s_cut;
    #pragma unroll
    for (int q = 0; q < 16; ++q) {
        unsigned int k = keys[q];
        if ((int)(k >> 20) <= cutbin) {
            unsigned int pos = atomicAdd(&s_m, 1u);
            if (pos < CAP)
                buf[pos] = ((unsigned long long)k << 32) | (unsigned int)(q * 256 + t);
        }
    }
    __syncthreads();
    unsigned int M = s_m; if (M > CAP) M = CAP;

    for (unsigned int c = t; c < M; c += 256) {
        unsigned long long mev = buf[c];
        unsigned int r = 0;
        for (unsigned int o = 0; o < M; ++o) r += (buf[o] < mev) ? 1u : 0u;
        if (r < KNNv) sel[r] = mev;
    }
    __syncthreads();

    if (t < KNNv) {
        unsigned long long p = sel[t];
        unsigned int k = (unsigned int)(p >> 32);
        int j = (int)(p & 0xffffffffu);
        float sv = __uint_as_float(k);
        bool nb = node_mask[(size_t)z * NN + j] != 0;
        bool em = (!mask_i && !nb) && (sv != 0.0f) && (sv < 144.0f);
        int kv = em ? j : i;
        size_t o = (size_t)bi * KNNv + t;
        out_kidx[o]  = (float)kv;
        out_emask[o] = em ? 1.0f : 0.0f;
    }
}

// ---------------- Edges: RBF+LN (bf16) -> MFMA GEMM ---------------------
// Block: 64 edges x 128 cols. Wave w owns cols [32w,32w+32), all 64 edges.
__global__ __launch_bounds__(256) void edge_kernel(
    const float* __restrict__ C,
    const float* __restrict__ kidxf,
    const float* __restrict__ centers,
    const unsigned short* __restrict__ Wt,   // bf16 (128 x 256), gamma folded
    const float* __restrict__ bias2,         // beta@W + b
    float* __restrict__ outE)
{
    __shared__ unsigned short Eln[64 * ELN_STR];   // normalized, bf16
    const int t = threadIdx.x;
    const long g0 = (long)blockIdx.x * 64;

    // ---- phase 1: 4 threads per edge; thread sub handles atom a=sub
    {
        const int e   = t >> 2;
        const int sub = t & 3;
        const long g = g0 + e;
        const int z   = (int)(g / (NN * KNNv));
        const int rem = (int)(g - (long)z * NN * KNNv);
        const int i   = rem / KNNv;
        const int j   = (int)kidxf[g];

        const float* Ci = C + (((size_t)z * NN + i) * 4 + sub) * 3;
        const float ax = Ci[0], ay = Ci[1], az = Ci[2];
        const float* Cj = C + ((size_t)z * NN + j) * 12;
        float d[4];
        #pragma unroll
        for (int b = 0; b < 4; ++b) {
            float dx = ax - Cj[b * 3 + 0];
            float dy = ay - Cj[b * 3 + 1];
            float dz = az - Cj[b * 3 + 2];
            float s = dx * dx + dy * dy + dz * dz;
            d[b] = s > 0.0f ? sqrtf(s) : 0.0f;
        }
        float cen[16];
        #pragma unroll
        for (int r = 0; r < 16; ++r) cen[r] = centers[r];

        float vals[64];
        float sum = 0.f, sumsq = 0.f;
        #pragma unroll
        for (int b = 0; b < 4; ++b) {
            #pragma unroll
            for (int r = 0; r < 16; ++r) {
                float dd = d[b] - cen[r];
                float v = __expf(dd * dd * -0.64f);
                vals[b * 16 + r] = v;
                sum += v; sumsq += v * v;
            }
        }
        sum   += __shfl_xor(sum, 1);   sum   += __shfl_xor(sum, 2);
        sumsq += __shfl_xor(sumsq, 1); sumsq += __shfl_xor(sumsq, 2);
        const float mu   = sum * (1.0f / 256.0f);
        const float var  = sumsq * (1.0f / 256.0f) - mu * mu;
        const float rstd = rsqrtf(var + 1e-5f);
        // store normalized (gamma/beta folded into Wt/bias2) as bf16
        #pragma unroll
        for (int w = 0; w < 8; ++w) {
            bf16x8 pk;
            #pragma unroll
            for (int v = 0; v < 8; ++v)
                pk[v] = (short)f2bf((vals[w * 8 + v] - mu) * rstd);
            *(bf16x8*)&Eln[e * ELN_STR + sub * 64 + w * 8] = pk;
        }
    }
    __syncthreads();

    // ---- phase 2: MFMA. wave -> 32 cols (2 n-tiles), 4 m-tiles of 16 edges
    {
        const int lane = t & 63;
        const int wv   = t >> 6;
        const int quad = lane >> 4;
        const int l15  = lane & 15;
        const int n0   = wv * 32;

        // B fragments in registers: one W read per wave per block
        bf16x8 Bf[2][8];
        #pragma unroll
        for (int nt = 0; nt < 2; ++nt)
            #pragma unroll
            for (int ks = 0; ks < 8; ++ks)
                Bf[nt][ks] = *(const bf16x8*)(Wt + (size_t)(n0 + nt * 16 + l15) * 256
                                                 + ks * 32 + quad * 8);

        fx4 acc[4][2];
        #pragma unroll
        for (int mt = 0; mt < 4; ++mt)
            #pragma unroll
            for (int nt = 0; nt < 2; ++nt)
                acc[mt][nt] = (fx4){0.f, 0.f, 0.f, 0.f};

        #pragma unroll
        for (int ks = 0; ks < 8; ++ks) {
            bf16x8 Af[4];
            #pragma unroll
            for (int mt = 0; mt < 4; ++mt)
                Af[mt] = *(const bf16x8*)&Eln[(mt * 16 + l15) * ELN_STR + ks * 32 + quad * 8];
            #pragma unroll
            for (int mt = 0; mt < 4; ++mt) {
                acc[mt][0] = __builtin_amdgcn_mfma_f32_16x16x32_bf16(Af[mt], Bf[0][ks], acc[mt][0], 0, 0, 0);
                acc[mt][1] = __builtin_amdgcn_mfma_f32_16x16x32_bf16(Af[mt], Bf[1][ks], acc[mt][1], 0, 0, 0);
            }
        }

        const float bb0 = bias2[n0 + l15];
        const float bb1 = bias2[n0 + 16 + l15];
        #pragma unroll
        for (int mt = 0; mt < 4; ++mt) {
            #pragma unroll
            for (int r = 0; r < 4; ++r) {
                const long row = g0 + mt * 16 + quad * 4 + r;
                float* orow = outE + (size_t)row * DM;
                orow[n0 + l15]      = acc[mt][0][r] + bb0;
                orow[n0 + 16 + l15] = acc[mt][1][r] + bb1;
            }
        }
    }
}

extern "C" void kernel_launch(void* const* d_in, const int* in_sizes, int n_in,
                              void* d_out, int out_size, void* d_ws, size_t ws_size,
                              hipStream_t stream) {
    const float* C          = (const float*)d_in[0];
    const unsigned char* nm = (const unsigned char*)d_in[1];
    const float* centers    = (const float*)d_in[2];
    const float* gamma_     = (const float*)d_in[3];
    const float* beta_      = (const float*)d_in[4];
    const float* W          = (const float*)d_in[5];
    const float* bias       = (const float*)d_in[6];

    float* out = (float*)d_out;
    const size_t nE = (size_t)ZB * NN * KNNv * DM;
    const size_t nK = (size_t)ZB * NN * KNNv;
    float* outE = out;
    float* outK = out + nE;
    float* outM = outK + nK;

    // workspace layout
    unsigned short* Wt   = (unsigned short*)d_ws;                 // 64 KiB
    float*          bias2 = (float*)((char*)d_ws + 65536);        // 512 B
    float4*         Ca4  = (float4*)((char*)d_ws + 66048);        // 128 KiB

    caprep_kernel<<<32, 256, 0, stream>>>(C, Ca4);
    wprep_kernel<<<32, 256, 0, stream>>>(W, gamma_, Wt);
    biasprep_kernel<<<1, 128, 0, stream>>>(W, beta_, bias, bias2);
    knn_kernel<<<ZB * NN, 256, 0, stream>>>(Ca4, nm, outK, outM);
    edge_kernel<<<(int)(nK / 64), 256, 0, stream>>>(C, outK, centers, Wt, bias2, outE);
}